// Round 11
// baseline (1806.566 us; speedup 1.0000x reference)
//
#include <hip/hip_runtime.h>
#include <math.h>

#define P 512
#define KC 10
#define NB 32
#define EPSV 0.01f
#define XT 17024   // padded columns: 16384 + per-class 64-alignment

typedef __attribute__((ext_vector_type(8))) __bf16 bf16x8;
typedef __attribute__((ext_vector_type(4))) float floatx4;

// ---------------- fused histogram + padded offsets + colmap scatter (one block) ----------------
__global__ __launch_bounds__(256) void sort_k(const int* __restrict__ Y, int* __restrict__ colmap,
                                              int* __restrict__ counts, int* __restrict__ off_pad,
                                              int* __restrict__ done, int m){
  __shared__ int cnt[KC], offp[KC + 1], cur[KC];
  int tid = threadIdx.x;
  if (tid == 0) *done = 0;
  if (tid < KC) cnt[tid] = 0;
  __syncthreads();
  for (int i = tid; i < m; i += 256){
    int y = Y[i];
    if (y >= 0 && y < KC) atomicAdd(&cnt[y], 1);
  }
  __syncthreads();
  if (tid == 0){
    int s = 0;
    for (int j = 0; j < KC; ++j){ offp[j] = s; s += ((cnt[j] + 63) >> 6) << 6; }
    offp[KC] = s;
  }
  __syncthreads();
  if (tid < KC){ cur[tid] = offp[tid]; counts[tid] = cnt[tid]; off_pad[tid] = offp[tid]; }
  if (tid == KC) off_pad[KC] = offp[KC];
  for (int i = tid; i < XT; i += 256) colmap[i] = -1;
  __syncthreads();
  for (int i = tid; i < m; i += 256){
    int y = Y[i];
    if (y >= 0 && y < KC){
      int pos = atomicAdd(&cur[y], 1);
      colmap[pos] = i;
    }
  }
}

// ---------------- transpose + split-bf16 convert: X[m][512] -> Xt_hi/lo[512][XT] ----------------
__global__ __launch_bounds__(256) void xt_k(const float* __restrict__ X, const int* __restrict__ colmap,
                                            __bf16* __restrict__ Xhi, __bf16* __restrict__ Xlo){
  __shared__ float T[64][65];
  int c0 = blockIdx.x * 64;
  int f0 = blockIdx.y * 64;
  int tid = threadIdx.x;

  int j = tid >> 2;
  int piece = tid & 3;
  int s = colmap[c0 + j];
  if (s >= 0){
    const float* src = X + (long)s * P + f0 + piece * 16;
    #pragma unroll
    for (int q = 0; q < 4; ++q){
      float4 v = *(const float4*)(src + q * 4);
      T[piece * 16 + q * 4 + 0][j] = v.x;
      T[piece * 16 + q * 4 + 1][j] = v.y;
      T[piece * 16 + q * 4 + 2][j] = v.z;
      T[piece * 16 + q * 4 + 3][j] = v.w;
    }
  } else {
    #pragma unroll
    for (int q = 0; q < 16; ++q) T[piece * 16 + q][j] = 0.f;
  }
  __syncthreads();

  int f = tid >> 2;
  int cp = (tid & 3) * 16;
  bf16x8 vh0, vl0, vh1, vl1;
  #pragma unroll
  for (int q = 0; q < 8; ++q){
    float x0 = T[f][cp + q];
    float x1 = T[f][cp + 8 + q];
    __bf16 h0 = (__bf16)x0, h1 = (__bf16)x1;
    vh0[q] = h0; vl0[q] = (__bf16)(x0 - (float)h0);
    vh1[q] = h1; vl1[q] = (__bf16)(x1 - (float)h1);
  }
  long base = (long)(f0 + f) * XT + c0 + cp;
  *(bf16x8*)&Xhi[base]     = vh0;
  *(bf16x8*)&Xhi[base + 8] = vh1;
  *(bf16x8*)&Xlo[base]     = vl0;
  *(bf16x8*)&Xlo[base + 8] = vl1;
}

// ---------------- per-class Gram via MFMA, split-bf16 ----------------
__global__ __launch_bounds__(256) void gram_mfma(const __bf16* __restrict__ Xhi,
                                                 const __bf16* __restrict__ Xlo,
                                                 const int* __restrict__ counts,
                                                 const int* __restrict__ off_pad,
                                                 float* __restrict__ Gk){
  int cls = blockIdx.y;
  int ta = 0, rem = blockIdx.x;
  while (rem >= ta + 1){ rem -= ta + 1; ++ta; }
  int tb = rem;
  int a0 = ta * 64, b0 = tb * 64;

  int tid  = threadIdx.x;
  int lane = tid & 63;
  int wv   = tid >> 6;
  int wrow = wv >> 1, wcol = wv & 1;
  int fr   = lane & 15;
  int quad = lane >> 4;

  int cs0     = off_pad[cls];
  int nchunks = (counts[cls] + 31) >> 5;

  long arow0 = (long)(a0 + wrow * 32 + fr) * XT;
  long brow0 = (long)(b0 + wcol * 32 + fr) * XT;

  floatx4 acc[2][2];
  #pragma unroll
  for (int i = 0; i < 2; ++i)
    #pragma unroll
    for (int j = 0; j < 2; ++j) acc[i][j] = (floatx4){0.f, 0.f, 0.f, 0.f};

  for (int ch = 0; ch < nchunks; ++ch){
    long co = cs0 + ch * 32 + quad * 8;
    bf16x8 ah[2], al[2], bh[2], bl[2];
    #pragma unroll
    for (int r = 0; r < 2; ++r){
      ah[r] = *(const bf16x8*)&Xhi[arow0 + (long)r * 16 * XT + co];
      al[r] = *(const bf16x8*)&Xlo[arow0 + (long)r * 16 * XT + co];
      bh[r] = *(const bf16x8*)&Xhi[brow0 + (long)r * 16 * XT + co];
      bl[r] = *(const bf16x8*)&Xlo[brow0 + (long)r * 16 * XT + co];
    }
    #pragma unroll
    for (int ri = 0; ri < 2; ++ri)
      #pragma unroll
      for (int rj = 0; rj < 2; ++rj){
        acc[ri][rj] = __builtin_amdgcn_mfma_f32_16x16x32_bf16(al[ri], bh[rj], acc[ri][rj], 0, 0, 0);
        acc[ri][rj] = __builtin_amdgcn_mfma_f32_16x16x32_bf16(ah[ri], bl[rj], acc[ri][rj], 0, 0, 0);
        acc[ri][rj] = __builtin_amdgcn_mfma_f32_16x16x32_bf16(ah[ri], bh[rj], acc[ri][rj], 0, 0, 0);
      }
  }

  float* C = Gk + (long)cls * P * P;
  #pragma unroll
  for (int ri = 0; ri < 2; ++ri){
    int a = a0 + wrow * 32 + ri * 16 + (lane >> 4) * 4;
    #pragma unroll
    for (int rj = 0; rj < 2; ++rj){
      int b = b0 + wcol * 32 + rj * 16 + (lane & 15);
      #pragma unroll
      for (int r = 0; r < 4; ++r)
        C[(long)(a + r) * P + b] = acc[ri][rj][r];
    }
  }
}

// ---------------- slot 10 = sum of class Grams ----------------
__global__ __launch_bounds__(256) void sum10_k(float* __restrict__ Gk){
  long i = (long)blockIdx.x * 256 + threadIdx.x;
  float4 s = {0.f, 0.f, 0.f, 0.f};
  #pragma unroll
  for (int j = 0; j < KC; ++j){
    float4 v = ((const float4*)(Gk + (long)j * P * P))[i];
    s.x += v.x; s.y += v.y; s.z += v.z; s.w += v.w;
  }
  ((float4*)(Gk + (long)KC * P * P))[i] = s;
}

// ---------------- LEFT-LOOKING MFMA Cholesky, overlapped factor + MFMA trsm ----------------
// Lg layout (R10): per matrix, step ch block at lb + ch*P*NB; row r at +r*NB.
// Per step s:
//  S1: diag-block GEMM K-split across 16 waves -> LDS atomicAdd into Dd.
//  S2: wave0: factor 32x32 (shfl regs) + Minv=L11^-1 (shfl regs) -> LDS bf16;
//      publish L11 rows; CONCURRENTLY waves 1..15: trailing GEMM + transform ->
//      per-wave LDS slab -> A-frags to regs (intra-wave only).
//  S3: waves 1..15: trsm = 6 MFMAs vs Minv; D -> slab -> packed bf16 -> Lg.
__global__ __launch_bounds__(1024) void chol_left(const float* __restrict__ Gk,
                                                  __bf16* __restrict__ Lghi,
                                                  __bf16* __restrict__ Lglo,
                                                  const int* __restrict__ counts,
                                                  float* __restrict__ logdets,
                                                  int* __restrict__ done,
                                                  float* __restrict__ out,
                                                  float m_tot){
  __shared__ float  Dd[NB * 33];          // hist-GEMM sum for diag block
  __shared__ float  Slab[16][16 * 36];    // per-wave staging tile (16 rows x 32 cols)
  __shared__ __bf16 Mh[NB * NB];          // Minv rows, bf16 hi
  __shared__ __bf16 Ml[NB * NB];          // Minv rows, bf16 lo

  int mat  = blockIdx.x;
  int tid  = threadIdx.x;
  int lane = tid & 63;
  int wv   = tid >> 6;
  int quad = lane >> 4;
  int fr   = lane & 15;
  const float* A = Gk + (long)mat * P * P;
  long lb = (long)mat * P * P;
  float sc = (mat < KC) ? ((float)P / (((float)counts[mat] + 1e-8f) * EPSV))
                        : ((float)P / (m_tot * EPSV));
  float loglocal = 0.f;

  for (int i = tid; i < NB * 33; i += 1024) Dd[i] = 0.f;
  __syncthreads();

  for (int s = 0; s < 16; ++s){
    int j0 = s * NB;
    int q  = P - j0;
    int nt3 = (q - NB) >> 4;    // 16-row trailing tiles

    // ==== S1: K-split diag-block GEMM -> Dd (atomic) ====
    if (s > 0){
      for (int it = wv; it < 2 * s; it += 16){
        int dt = it & 1;        // which 16-row half of the diag block
        int ch = it >> 1;       // which K chunk
        long cbase = lb + (long)ch * P * NB;
        long aoff = cbase + (long)(j0 + dt * 16 + fr) * NB + quad * 8;
        bf16x8 ah = *(const bf16x8*)&Lghi[aoff];
        bf16x8 al = *(const bf16x8*)&Lglo[aoff];
        #pragma unroll
        for (int h2 = 0; h2 < 2; ++h2){
          long boff = cbase + (long)(j0 + h2 * 16 + fr) * NB + quad * 8;
          bf16x8 bh = *(const bf16x8*)&Lghi[boff];
          bf16x8 bl = *(const bf16x8*)&Lglo[boff];
          floatx4 acc = {0.f, 0.f, 0.f, 0.f};
          acc = __builtin_amdgcn_mfma_f32_16x16x32_bf16(al, bh, acc, 0, 0, 0);
          acc = __builtin_amdgcn_mfma_f32_16x16x32_bf16(ah, bl, acc, 0, 0, 0);
          acc = __builtin_amdgcn_mfma_f32_16x16x32_bf16(ah, bh, acc, 0, 0, 0);
          #pragma unroll
          for (int r = 0; r < 4; ++r)
            atomicAdd(&Dd[(dt * 16 + quad * 4 + r) * 33 + h2 * 16 + fr], acc[r]);
        }
      }
    }
    __syncthreads();   // B1: Dd complete

    int myidx[2] = {-1, -1};
    int mygr0[2] = {0, 0};
    bf16x8 afh[2], afl[2];

    if (wv == 0){
      // ==== S2 (wave 0): transform+factor diag, build Minv, publish L11 ====
      float a[NB];
      float myp = 1.f;
      if (lane < NB){
        const float* g = A + (long)(j0 + lane) * P + j0;
        #pragma unroll
        for (int u = 0; u < NB; u += 4){
          float4 v = *(const float4*)(g + u);
          a[u+0] = sc * v.x - Dd[lane * 33 + u + 0];
          a[u+1] = sc * v.y - Dd[lane * 33 + u + 1];
          a[u+2] = sc * v.z - Dd[lane * 33 + u + 2];
          a[u+3] = sc * v.w - Dd[lane * 33 + u + 3];
        }
        a[lane] += 1.0f;
      } else {
        #pragma unroll
        for (int u = 0; u < NB; ++u) a[u] = 0.f;
      }
      #pragma unroll
      for (int jj = 0; jj < NB; ++jj){
        float d = __shfl(a[jj], jj);
        if (lane == jj) myp = d;
        float inv = 1.0f / d;
        float rs  = rsqrtf(d);
        float w   = a[jj] * inv;
        #pragma unroll
        for (int l = jj + 1; l < NB; ++l){
          float prl = __shfl(a[l], jj);
          if (lane > jj) a[l] -= w * prl;
        }
        if (lane >= jj) a[jj] *= rs;
      }
      // Minv via shfl: lane c holds column c -> x[r] = Minv[r][c]
      float x[NB];
      #pragma unroll
      for (int r2 = 0; r2 < NB; ++r2){
        float acc2 = (r2 == lane) ? 1.f : 0.f;
        #pragma unroll
        for (int u = 0; u < r2; ++u){
          float Lru = __shfl(a[u], r2);
          acc2 -= Lru * x[u];
        }
        float dr = __shfl(a[r2], r2);
        x[r2] = acc2 / dr;
      }
      if (lane < NB){
        #pragma unroll
        for (int r2 = 0; r2 < NB; ++r2){
          __bf16 h = (__bf16)x[r2];
          Mh[r2 * NB + lane] = h;
          Ml[r2 * NB + lane] = (__bf16)(x[r2] - (float)h);
        }
        // publish L11 rows (upper tri zeroed)
        float b[NB];
        #pragma unroll
        for (int u = 0; u < NB; ++u) b[u] = (u > lane) ? 0.f : a[u];
        long rbase = lb + (long)s * P * NB + (long)(j0 + lane) * NB;
        #pragma unroll
        for (int c4 = 0; c4 < NB; c4 += 8){
          bf16x8 vh, vl;
          #pragma unroll
          for (int u = 0; u < 8; ++u){
            float f = b[c4 + u];
            __bf16 h = (__bf16)f;
            vh[u] = h; vl[u] = (__bf16)(f - (float)h);
          }
          *(bf16x8*)&Lghi[rbase + c4] = vh;
          *(bf16x8*)&Lglo[rbase + c4] = vl;
        }
      }
      loglocal += logf(myp);
    } else {
      // ==== S2' (waves 1..15): trailing GEMM + transform + stage + A-frags ====
      #pragma unroll
      for (int t = 0; t < 2; ++t){
        int idx = (wv - 1) + 15 * t;
        if (idx < nt3){
          myidx[t] = idx;
          int gr0 = j0 + NB + idx * 16;
          mygr0[t] = gr0;
          floatx4 acc[2] = {{0.f,0.f,0.f,0.f},{0.f,0.f,0.f,0.f}};
          for (int ch = 0; ch < s; ++ch){
            long cbase = lb + (long)ch * P * NB;
            long aoff = cbase + (long)(gr0 + fr) * NB + quad * 8;
            bf16x8 ah = *(const bf16x8*)&Lghi[aoff];
            bf16x8 al = *(const bf16x8*)&Lglo[aoff];
            #pragma unroll
            for (int h2 = 0; h2 < 2; ++h2){
              long boff = cbase + (long)(j0 + h2 * 16 + fr) * NB + quad * 8;
              bf16x8 bh = *(const bf16x8*)&Lghi[boff];
              bf16x8 bl = *(const bf16x8*)&Lglo[boff];
              acc[h2] = __builtin_amdgcn_mfma_f32_16x16x32_bf16(al, bh, acc[h2], 0, 0, 0);
              acc[h2] = __builtin_amdgcn_mfma_f32_16x16x32_bf16(ah, bl, acc[h2], 0, 0, 0);
              acc[h2] = __builtin_amdgcn_mfma_f32_16x16x32_bf16(ah, bh, acc[h2], 0, 0, 0);
            }
          }
          // transform (rows strictly below diag: no +I) + stage to slab
          #pragma unroll
          for (int h2 = 0; h2 < 2; ++h2){
            #pragma unroll
            for (int r = 0; r < 4; ++r){
              int grow = gr0 + quad * 4 + r;
              int gcol = j0 + h2 * 16 + fr;
              float v = sc * A[(long)grow * P + gcol] - acc[h2][r];
              Slab[wv][(quad * 4 + r) * 36 + h2 * 16 + fr] = v;
            }
          }
          // A-frag: lane m=fr, k=quad*8+j  (intra-wave LDS RAW, no barrier)
          float4 p0 = *(const float4*)&Slab[wv][fr * 36 + quad * 8];
          float4 p1 = *(const float4*)&Slab[wv][fr * 36 + quad * 8 + 4];
          float pv[8] = {p0.x, p0.y, p0.z, p0.w, p1.x, p1.y, p1.z, p1.w};
          #pragma unroll
          for (int u = 0; u < 8; ++u){
            __bf16 h = (__bf16)pv[u];
            afh[t][u] = h; afl[t][u] = (__bf16)(pv[u] - (float)h);
          }
        }
      }
    }
    __syncthreads();   // B2: Minv ready

    // ==== S3: trsm via MFMA vs Minv; write L21 coalesced ====
    if (wv >= 1){
      #pragma unroll
      for (int t = 0; t < 2; ++t){
        if (myidx[t] >= 0){
          #pragma unroll
          for (int h2 = 0; h2 < 2; ++h2){
            bf16x8 bh = *(const bf16x8*)&Mh[(h2 * 16 + fr) * NB + quad * 8];
            bf16x8 bl = *(const bf16x8*)&Ml[(h2 * 16 + fr) * NB + quad * 8];
            floatx4 acc = {0.f, 0.f, 0.f, 0.f};
            acc = __builtin_amdgcn_mfma_f32_16x16x32_bf16(afl[t], bh, acc, 0, 0, 0);
            acc = __builtin_amdgcn_mfma_f32_16x16x32_bf16(afh[t], bl, acc, 0, 0, 0);
            acc = __builtin_amdgcn_mfma_f32_16x16x32_bf16(afh[t], bh, acc, 0, 0, 0);
            #pragma unroll
            for (int r = 0; r < 4; ++r)
              Slab[wv][(quad * 4 + r) * 36 + h2 * 16 + fr] = acc[r];
          }
          // repack: lane handles row (lane&15), col-block (lane>>4)*8
          int rr = lane & 15;
          int cb = (lane >> 4) * 8;
          float4 q0 = *(const float4*)&Slab[wv][rr * 36 + cb];
          float4 q1 = *(const float4*)&Slab[wv][rr * 36 + cb + 4];
          float qv[8] = {q0.x, q0.y, q0.z, q0.w, q1.x, q1.y, q1.z, q1.w};
          bf16x8 vh, vl;
          #pragma unroll
          for (int u = 0; u < 8; ++u){
            __bf16 h = (__bf16)qv[u];
            vh[u] = h; vl[u] = (__bf16)(qv[u] - (float)h);
          }
          long rb = lb + (long)s * P * NB + (long)(mygr0[t] + rr) * NB + cb;
          *(bf16x8*)&Lghi[rb] = vh;
          *(bf16x8*)&Lglo[rb] = vl;
        }
      }
    }
    // zero Dd for next step (safe: last read was in S2 before B2)
    for (int i = tid; i < NB * 33; i += 1024) Dd[i] = 0.f;
    __syncthreads();   // B3: Lg visible for next step's GEMM; Dd zeroed
  }

  // ==== epilogue: reduce logs; publish; last block computes outputs ====
  if (wv == 0){
    float lp = loglocal;
    #pragma unroll
    for (int off = 32; off >= 1; off >>= 1) lp += __shfl_xor(lp, off);
    if (lane == 0){
      __hip_atomic_store(&logdets[mat], lp, __ATOMIC_RELEASE, __HIP_MEMORY_SCOPE_AGENT);
      int old = __hip_atomic_fetch_add(done, 1, __ATOMIC_ACQ_REL, __HIP_MEMORY_SCOPE_AGENT);
      if (old == KC){
        float ld[KC + 1];
        #pragma unroll
        for (int j = 0; j <= KC; ++j)
          ld[j] = __hip_atomic_load(&logdets[j], __ATOMIC_ACQUIRE, __HIP_MEMORY_SCOPE_AGENT);
        out[0] = 0.5f * ld[KC];
        float comp = 0.f;
        for (int j = 0; j < KC; ++j){
          float trPi = (float)counts[j] + 1e-8f;
          comp += ld[j] * trPi / m_tot;
        }
        out[1] = 0.5f * comp;
      }
    }
  }
}

extern "C" void kernel_launch(void* const* d_in, const int* in_sizes, int n_in,
                              void* d_out, int out_size, void* d_ws, size_t ws_size,
                              hipStream_t stream) {
  (void)n_in; (void)out_size; (void)ws_size;
  const float* X = (const float*)d_in[0];
  const int*   Y = (const int*)d_in[1];
  int m = in_sizes[0] / P;     // 16384

  float*  Gk      = (float*)d_ws;                    // 11 * P*P floats
  __bf16* Xhi     = (__bf16*)(Gk + 11L * P * P);     // 512*XT bf16
  __bf16* Xlo     = Xhi + (long)P * XT;              // 512*XT bf16
  int*    colmap  = (int*)(Xlo + (long)P * XT);      // XT ints
  int*    counts  = colmap + XT;                     // 16
  int*    off_pad = counts + 16;                     // 17
  int*    done    = off_pad + 17;                    // 1
  float*  logdets = (float*)(done + 1);              // 16

  // L planes alias the X planes (dead after gram_mfma); 11*P*P <= P*XT
  __bf16* Lghi = Xhi;
  __bf16* Lglo = Xlo;

  sort_k<<<1, 256, 0, stream>>>(Y, colmap, counts, off_pad, done, m);

  dim3 xg(XT / 64, 8);
  xt_k<<<xg, 256, 0, stream>>>(X, colmap, Xhi, Xlo);

  dim3 gg(36, KC);
  gram_mfma<<<gg, 256, 0, stream>>>(Xhi, Xlo, counts, off_pad, Gk);

  sum10_k<<<P * P / 1024, 256, 0, stream>>>(Gk);

  chol_left<<<KC + 1, 1024, 0, stream>>>(Gk, Lghi, Lglo, counts, logdets, done,
                                         (float*)d_out, (float)m);
}